// Round 5
// baseline (185.237 us; speedup 1.0000x reference)
//
#include <hip/hip_runtime.h>
#include <hip/hip_cooperative_groups.h>

namespace cg = cooperative_groups;

// CrossAttention collapses algebraically (K/V from a 1-channel map):
//   attn[b,j,i] = softmax_i(a_j * d_i),  a_j = g . seg[b,:,j] + h
//   out[b,o,j]  = u[o] * S1(a_j) + w[o]
// S1(a) = sum_i d_i e^{a d_i} / sum_i e^{a d_i}, S1'(a) = Var_a(d).
// {S1, dS1} tabulated on a FIXED sinh-warped grid a(x)=2sinh(beta*x),
// x in [-1,1], beta=asinh(32) (domain +-64 ~ 8 sigma of a; overflow
// harmless: S1 saturates). Single cooperative kernel: phase 1 overlaps
// seg prefetch + a_j + weight folds with the table's exp loop; grid.sync();
// phase 2 Hermite-interps and does the rank-1 broadcast store.

#define B 8
#define N 4096           // H*W
#define INC 19
#define OUTC 64
#define T 512
#define LOG2E 1.4426950408889634f
#define BETA 4.15912713f          // asinh(32)
#define INV_BETA_LN2 0.16665683f  // ln2 / beta
#define DX (2.0f / 511.0f)        // node spacing in x

// ws float layout: [0 .. 8*T*2): (b*T + t)*2 + {S1, dS1/dnode}

// grid 512 = 8 batches x 64 tiles (64 queries each), 256 threads.
__global__ __launch_bounds__(256) void fused_kernel(
    const float* __restrict__ seg, const float* __restrict__ dep,
    const float* __restrict__ Wq, const float* __restrict__ bq,
    const float* __restrict__ Wk, const float* __restrict__ Wv,
    const float* __restrict__ bv, const float* __restrict__ Wo,
    const float* __restrict__ bo, float* __restrict__ ws,
    float* __restrict__ out) {
  __shared__ float sd[N];          // depth row (16 KB)
  __shared__ float s_g[INC + 1];
  __shared__ float s_u[OUTC], s_w[OUTC];
  __shared__ float s_S1[64];
  __shared__ float s_mn[2], s_mx[2];

  const int tid = threadIdx.x;
  const int b = blockIdx.x >> 6;
  const int tile = blockIdx.x & 63;

  // ---- phase 1a: three-way work split (no dependency between lanes) ----
  float sv[INC];                   // live only in tid<64
  if (tid < 64) {
    // prefetch this tile's 64 queries x 19 channels (coalesced per wave)
    const float* sp = seg + (size_t)b * INC * N + (tile << 6) + tid;
    #pragma unroll
    for (int c = 0; c < INC; ++c) sv[c] = sp[(size_t)c << 12];
  } else if (tid < 192) {
    // stage depth row + min/max (128 threads, 8 float4 each)
    const float4* d4 = (const float4*)(dep + ((size_t)b << 12));
    float mn = 1e30f, mx = -1e30f;
    #pragma unroll
    for (int i = tid - 64; i < N / 4; i += 128) {
      float4 v = d4[i];
      ((float4*)sd)[i] = v;
      mn = fminf(mn, fminf(fminf(v.x, v.y), fminf(v.z, v.w)));
      mx = fmaxf(mx, fmaxf(fmaxf(v.x, v.y), fmaxf(v.z, v.w)));
    }
    #pragma unroll
    for (int off = 32; off >= 1; off >>= 1) {
      mn = fminf(mn, __shfl_xor(mn, off));
      mx = fmaxf(mx, __shfl_xor(mx, off));
    }
    if ((tid & 63) == 0) { s_mn[(tid >> 6) - 1] = mn; s_mx[(tid >> 6) - 1] = mx; }
  } else {
    const int t2 = tid - 192;
    // fold u = Wo@Wv, w = Wo@bv + bo (one output row per thread)
    const float* wr = Wo + t2 * OUTC;
    float u = 0.f, w = 0.f;
    #pragma unroll
    for (int c = 0; c < OUTC; ++c) {
      float wo = wr[c];
      u = fmaf(wo, Wv[c], u);
      w = fmaf(wo, bv[c], w);
    }
    s_u[t2] = u;
    s_w[t2] = w + bo[t2];
    if (t2 < INC) {
      float g = 0.f;
      #pragma unroll
      for (int o = 0; o < OUTC; ++o) g = fmaf(Wq[o * INC + t2], Wk[o], g);
      s_g[t2] = g;
    } else if (t2 == INC) {
      float h = 0.f;
      #pragma unroll
      for (int o = 0; o < OUTC; ++o) h = fmaf(bq[o], Wk[o], h);
      s_g[INC] = h;
    }
  }
  __syncthreads();

  // ---- phase 1b: a_j for this tile's queries (kept in register) ----
  float a_q = 0.f;
  if (tid < 64) {
    float a = s_g[INC];
    #pragma unroll
    for (int c = 0; c < INC; ++c) a = fmaf(sv[c], s_g[c], a);
    a_q = a;
  }

  // ---- phase 1c: 8 table points/block over all 4096 keys ----
  const float dmn = fminf(s_mn[0], s_mn[1]);
  const float dmx = fmaxf(s_mx[0], s_mx[1]);
  const int grp = tid >> 5, lane = tid & 31;
  const int tpt = (tile << 3) + grp;          // 64 tiles x 8 = T points
  const float x = (float)tpt * DX - 1.0f;
  const float ep = __expf(BETA * x), en = 1.0f / ep;
  const float a_t = ep - en;                  // 2*sinh(beta*x)
  const float dadx = BETA * (ep + en);        // da/dx
  const float a2 = a_t * LOG2E;
  const float m2n = -fmaxf(a2 * dmn, a2 * dmx);
  float s0 = 0.f, s1 = 0.f, s2 = 0.f;
  const float4* sd4 = (const float4*)sd;
  #pragma unroll 4
  for (int r = 0; r < 32; ++r) {
    float4 v = sd4[(r << 5) + lane];
    float e0 = __builtin_amdgcn_exp2f(fmaf(a2, v.x, m2n));
    float e1 = __builtin_amdgcn_exp2f(fmaf(a2, v.y, m2n));
    float e2 = __builtin_amdgcn_exp2f(fmaf(a2, v.z, m2n));
    float e3 = __builtin_amdgcn_exp2f(fmaf(a2, v.w, m2n));
    float t0 = v.x * e0, t1 = v.y * e1, t2 = v.z * e2, t3 = v.w * e3;
    s0 += e0 + e1 + e2 + e3;
    s1 += t0 + t1 + t2 + t3;
    s2 = fmaf(v.x, t0, s2); s2 = fmaf(v.y, t1, s2);
    s2 = fmaf(v.z, t2, s2); s2 = fmaf(v.w, t3, s2);
  }
  #pragma unroll
  for (int off = 16; off >= 1; off >>= 1) {
    s0 += __shfl_xor(s0, off);
    s1 += __shfl_xor(s1, off);
    s2 += __shfl_xor(s2, off);
  }
  if (lane == 0) {
    const float inv = 1.0f / s0;
    const float r1 = s1 * inv;
    const float var = fmaf(-r1, r1, s2 * inv);
    ((float2*)ws)[b * T + tpt] = make_float2(r1, var * dadx * DX);
  }

  // ---- table visible device-wide, then grid barrier ----
  __threadfence();
  cg::this_grid().sync();
  __threadfence();

  // ---- phase 2: Hermite interp S1(a_j) ----
  if (tid < 64) {
    const float z = 0.5f * a_q;
    const float xq = __log2f(z + __fsqrt_rn(fmaf(z, z, 1.0f))) * INV_BETA_LN2;
    float uu = fminf(fmaxf(fmaf(xq, 255.5f, 255.5f), 0.0f), 511.0f);
    int i = (int)uu;
    i = i > (T - 2) ? (T - 2) : i;
    const float xf = uu - (float)i;
    const float2* tb = (const float2*)ws + b * T + i;
    const float2 p0 = tb[0], p1 = tb[1];
    const float xf2 = xf * xf, xf3 = xf2 * xf;
    const float h00 = 2.f * xf3 - 3.f * xf2 + 1.f;
    const float h10 = xf3 - 2.f * xf2 + xf;
    const float h11 = xf3 - xf2;
    s_S1[tid] = h00 * p0.x + (1.f - h00) * p1.x + h10 * p0.y + h11 * p1.y;
  }
  __syncthreads();

  // ---- phase 3: out[b,o,tile*64+q] = u[o]*S1[q] + w[o] ----
  float* ob = out + ((size_t)b << 18) + (tile << 6);
  const float4* s14 = (const float4*)s_S1;
  #pragma unroll
  for (int rep = 0; rep < 4; ++rep) {
    int idx = (rep << 8) + tid;        // 64 rows x 16 float4
    int o = idx >> 4, q4 = idx & 15;
    float u = s_u[o], w = s_w[o];
    float4 s = s14[q4];
    ((float4*)(ob + ((size_t)o << 12)))[q4] =
        make_float4(fmaf(u, s.x, w), fmaf(u, s.y, w),
                    fmaf(u, s.z, w), fmaf(u, s.w, w));
  }
}

extern "C" void kernel_launch(void* const* d_in, const int* in_sizes, int n_in,
                              void* d_out, int out_size, void* d_ws, size_t ws_size,
                              hipStream_t stream) {
  const float* seg = (const float*)d_in[0];
  const float* dep = (const float*)d_in[1];
  const float* Wq  = (const float*)d_in[2];
  const float* bq  = (const float*)d_in[3];
  const float* Wk  = (const float*)d_in[4];
  // d_in[5] = bk: cancels in softmax, unused
  const float* Wv  = (const float*)d_in[6];
  const float* bv  = (const float*)d_in[7];
  const float* Wo  = (const float*)d_in[8];
  const float* bo  = (const float*)d_in[9];
  float* out = (float*)d_out;
  float* ws  = (float*)d_ws;

  void* args[] = {&seg, &dep, &Wq, &bq, &Wk, &Wv, &bv, &Wo, &bo, &ws, &out};
  hipLaunchCooperativeKernel((void*)fused_kernel, dim3(B * 64), dim3(256),
                             args, 0, stream);
}

// Round 6
// 83.595 us; speedup vs baseline: 2.2159x; 2.2159x over previous
//
#include <hip/hip_runtime.h>

// CrossAttention collapses algebraically (K/V from a 1-channel map):
//   attn[b,j,i] = softmax_i(a_j * d_i),  a_j = g . seg[b,:,j] + h
//   out[b,o,j]  = u[o] * S1(a_j) + w[o]
// S1(a) = sum_i d_i e^{a d_i} / sum_i e^{a d_i}, S1'(a) = Var_a(d).
// Table on a FIXED sinh-warped grid a(x) = 2 sinh(beta*x), x in [-1,1],
// beta = asinh(32) -> domain +-64 (8 sigma of a's N(0,8^2) distribution;
// overflow is harmless: S1 saturates).
// R5 post-mortem: cooperative grid.sync costs ~80us on MI355X (device-scope
// barrier across 8 XCDs) -- two stream-ordered kernels are far cheaper.
// This is R4's structure with T=256 (halved table work; Hermite err ~5e-6).

#define B 8
#define N 4096           // H*W
#define INC 19
#define OUTC 64
#define T 256
#define LOG2E 1.4426950408889634f
#define BETA 4.15912713f          // asinh(32)
#define INV_BETA_LN2 0.16665683f  // ln2 / beta
#define DX (2.0f / 255.0f)        // node spacing in x

// ws float layout: [0 .. 8*T*2) table: (b*T + t)*2 + {S1, dS1/dnode}

// ---- Kernel T: build table. grid 256 = 8 batches x 32, 8 pts/block ----
__global__ __launch_bounds__(256) void table_kernel(
    const float* __restrict__ dep, float* __restrict__ ws) {
  __shared__ float sd[N];
  __shared__ float s_mn[4], s_mx[4];
  const int tid = threadIdx.x;
  const int b = blockIdx.x >> 5;
  const int g32 = blockIdx.x & 31;

  const float4* d4 = (const float4*)(dep + ((size_t)b << 12));
  float mn = 1e30f, mx = -1e30f;
  #pragma unroll
  for (int i = tid; i < N / 4; i += 256) {
    float4 v = d4[i];
    ((float4*)sd)[i] = v;
    mn = fminf(mn, fminf(fminf(v.x, v.y), fminf(v.z, v.w)));
    mx = fmaxf(mx, fmaxf(fmaxf(v.x, v.y), fmaxf(v.z, v.w)));
  }
  #pragma unroll
  for (int off = 32; off >= 1; off >>= 1) {
    mn = fminf(mn, __shfl_xor(mn, off));
    mx = fmaxf(mx, __shfl_xor(mx, off));
  }
  if ((tid & 63) == 0) { s_mn[tid >> 6] = mn; s_mx[tid >> 6] = mx; }
  __syncthreads();

  const float dmn = fminf(fminf(s_mn[0], s_mn[1]), fminf(s_mn[2], s_mn[3]));
  const float dmx = fmaxf(fmaxf(s_mx[0], s_mx[1]), fmaxf(s_mx[2], s_mx[3]));

  // 8 groups of 32 lanes; group computes grid point t over all 4096 keys.
  const int grp = tid >> 5, lane = tid & 31;
  const int t = (g32 << 3) + grp;
  const float x = (float)t * DX - 1.0f;
  const float ep = __expf(BETA * x), en = 1.0f / ep;
  const float a = ep - en;                 // 2*sinh(beta*x)
  const float dadx = BETA * (ep + en);     // da/dx
  const float a2 = a * LOG2E;
  const float m2n = -fmaxf(a2 * dmn, a2 * dmx);
  float s0 = 0.f, s1 = 0.f, s2 = 0.f;
  const float4* sd4 = (const float4*)sd;
  #pragma unroll 4
  for (int r = 0; r < 32; ++r) {
    float4 v = sd4[(r << 5) + lane];
    float e0 = __builtin_amdgcn_exp2f(fmaf(a2, v.x, m2n));
    float e1 = __builtin_amdgcn_exp2f(fmaf(a2, v.y, m2n));
    float e2 = __builtin_amdgcn_exp2f(fmaf(a2, v.z, m2n));
    float e3 = __builtin_amdgcn_exp2f(fmaf(a2, v.w, m2n));
    float t0 = v.x * e0, t1 = v.y * e1, t2 = v.z * e2, t3 = v.w * e3;
    s0 += e0 + e1 + e2 + e3;
    s1 += t0 + t1 + t2 + t3;
    s2 = fmaf(v.x, t0, s2); s2 = fmaf(v.y, t1, s2);
    s2 = fmaf(v.z, t2, s2); s2 = fmaf(v.w, t3, s2);
  }
  #pragma unroll
  for (int off = 16; off >= 1; off >>= 1) {
    s0 += __shfl_xor(s0, off);
    s1 += __shfl_xor(s1, off);
    s2 += __shfl_xor(s2, off);
  }
  if (lane == 0) {
    const float inv = 1.0f / s0;
    const float r1 = s1 * inv;
    const float var = fmaf(-r1, r1, s2 * inv);
    ws[((b * T + t) << 1)] = r1;
    ws[((b * T + t) << 1) + 1] = var * dadx * DX;  // dS1/dnode
  }
}

// ---- Kernel Q: fold weights, a_j, Hermite interp, rank-1 store ----
// grid 256 = 8 batches x 32 tiles (128 queries), 256 threads.
__global__ __launch_bounds__(256) void query_kernel(
    const float* __restrict__ seg, const float* __restrict__ Wq,
    const float* __restrict__ bq, const float* __restrict__ Wk,
    const float* __restrict__ Wv, const float* __restrict__ bv,
    const float* __restrict__ Wo, const float* __restrict__ bo,
    const float* __restrict__ ws, float* __restrict__ out) {
  __shared__ float s_g[INC + 1];
  __shared__ float s_u[OUTC], s_w[OUTC];
  __shared__ float s_S1[128];
  const int tid = threadIdx.x;
  const int b = blockIdx.x >> 5;
  const int qbase = (blockIdx.x & 31) << 7;

  float sv[INC];
  if (tid < 128) {
    // prefetch this query's 19 channel values (coalesced per wave)
    const float* sp = seg + (size_t)b * INC * N + qbase + tid;
    #pragma unroll
    for (int c = 0; c < INC; ++c) sv[c] = sp[(size_t)c << 12];
  } else {
    const int t2 = tid - 128;
    if (t2 < OUTC) {
      const float* wr = Wo + t2 * OUTC;
      float u = 0.f, w = 0.f;
      #pragma unroll
      for (int c = 0; c < OUTC; ++c) {
        float wo = wr[c];
        u = fmaf(wo, Wv[c], u);
        w = fmaf(wo, bv[c], w);
      }
      s_u[t2] = u;
      s_w[t2] = w + bo[t2];
    } else if (t2 < OUTC + INC) {
      const int c = t2 - OUTC;
      float g = 0.f;
      #pragma unroll
      for (int o = 0; o < OUTC; ++o) g = fmaf(Wq[o * INC + c], Wk[o], g);
      s_g[c] = g;
    } else if (t2 == OUTC + INC) {
      float h = 0.f;
      #pragma unroll
      for (int o = 0; o < OUTC; ++o) h = fmaf(bq[o], Wk[o], h);
      s_g[INC] = h;
    }
  }
  __syncthreads();

  if (tid < 128) {
    float a = s_g[INC];
    #pragma unroll
    for (int c = 0; c < INC; ++c) a = fmaf(sv[c], s_g[c], a);
    // invert warp: x = asinh(a/2)/beta = log2(z + sqrt(z^2+1)) * ln2/beta
    const float z = 0.5f * a;
    const float x = __log2f(z + __fsqrt_rn(fmaf(z, z, 1.0f))) * INV_BETA_LN2;
    float uu = fminf(fmaxf(fmaf(x, 127.5f, 127.5f), 0.0f), 255.0f);
    int i = (int)uu;
    i = i > (T - 2) ? (T - 2) : i;
    const float xf = uu - (float)i;
    const float* tb = ws + ((b * T + i) << 1);
    const float y0 = tb[0], m0 = tb[1], y1 = tb[2], m1 = tb[3];
    const float xf2 = xf * xf, xf3 = xf2 * xf;
    const float h00 = 2.f * xf3 - 3.f * xf2 + 1.f;
    const float h10 = xf3 - 2.f * xf2 + xf;
    const float h11 = xf3 - xf2;
    s_S1[tid] = h00 * y0 + (1.f - h00) * y1 + h10 * m0 + h11 * m1;
  }
  __syncthreads();

  // out[b,o,qbase+q] = u[o]*S1[q] + w[o]; 64 rows x 32 float4, 8 per thread
  float* ob = out + ((size_t)b << 18) + qbase;
  const float4* s14 = (const float4*)s_S1;
  #pragma unroll
  for (int rep = 0; rep < 8; ++rep) {
    int idx = (rep << 8) + tid;
    int o = idx >> 5, q4 = idx & 31;
    float u = s_u[o], w = s_w[o];
    float4 s = s14[q4];
    ((float4*)(ob + ((size_t)o << 12)))[q4] =
        make_float4(fmaf(u, s.x, w), fmaf(u, s.y, w),
                    fmaf(u, s.z, w), fmaf(u, s.w, w));
  }
}

extern "C" void kernel_launch(void* const* d_in, const int* in_sizes, int n_in,
                              void* d_out, int out_size, void* d_ws, size_t ws_size,
                              hipStream_t stream) {
  const float* seg = (const float*)d_in[0];
  const float* dep = (const float*)d_in[1];
  const float* Wq  = (const float*)d_in[2];
  const float* bq  = (const float*)d_in[3];
  const float* Wk  = (const float*)d_in[4];
  // d_in[5] = bk: cancels in softmax, unused
  const float* Wv  = (const float*)d_in[6];
  const float* bv  = (const float*)d_in[7];
  const float* Wo  = (const float*)d_in[8];
  const float* bo  = (const float*)d_in[9];
  float* out = (float*)d_out;
  float* ws  = (float*)d_ws;

  table_kernel<<<B * 32, 256, 0, stream>>>(dep, ws);
  query_kernel<<<B * 32, 256, 0, stream>>>(seg, Wq, bq, Wk, Wv, bv, Wo, bo,
                                           ws, out);
}